// Round 1
// 24203.180 us; speedup vs baseline: 3.7126x; 3.7126x over previous
//
#include <hip/hip_runtime.h>
#include <cstddef>

// ---------------------------------------------------------------------------
// CharRNN BN-LSTM (2 layers, recurrent batch norm) + projection + softmax head
// Round 2: restructure recurrent phase kernel from latency-bound uniform
// weight loads -> register-tiled VALU GEMM with coalesced lane-parallel loads.
//   - per block: 8 H-columns (32 gate cols) of ONE layer; layers split across
//     blocks (they are independent within a phase)
//   - wave lane = (batch-group, col-group); each lane keeps an 8x4 acc tile
//   - K split over 4 waves; padded-LDS reduce; wave-level BN (lane = batch)
// ---------------------------------------------------------------------------

namespace {
constexpr int kT  = 128;
constexpr int kB  = 64;
constexpr int kNU = 256;
constexpr int kH  = 1024;
constexpr int kV  = 8000;
constexpr int kHB = kH * kB;   // 65536 floats
constexpr int k4H = 4096;
}

__device__ __forceinline__ float wave_sum64(float v) {
#pragma unroll
  for (int off = 32; off > 0; off >>= 1) v += __shfl_xor(v, off, 64);
  return v;
}

__device__ __forceinline__ float sigm(float x) { return 1.0f / (1.0f + expf(-x)); }

struct RecParams {
  const float* xT;      // [T][NU][B]
  float* h0T;           // [2][H][B] double buffer
  float* h1hist;        // [T+1][H][B]
  float* c0T;           // [H][B]
  float* c1T;           // [H][B]
  const float* Wx0; const float* Wh0; const float* b0;
  const float* gx0; const float* gh0; const float* gc0; const float* bc0;
  const float* Wx1; const float* Wh1; const float* b1;
  const float* gx1; const float* gh1; const float* gc1; const float* bc1;
};

// Per-wave K-slice of GEMM: acc[i][j] += act[u][bg*8+i] * W[u][wcol+j]
// act: [K][64] (transposed activations), W: [K][4096] row-major.
__device__ __forceinline__ void gemm_slice(const float* __restrict__ act,
                                           const float* __restrict__ W,
                                           int u0, int ks, int bg, int wcol,
                                           float acc[8][4]) {
  const float* ap = act + (size_t)u0 * 64 + bg * 8;
  const float* wp = W + (size_t)u0 * k4H + wcol;
#pragma unroll 4
  for (int u = 0; u < ks; ++u) {
    const float4 a0 = *(const float4*)(ap);
    const float4 a1 = *(const float4*)(ap + 4);
    const float4 wv = *(const float4*)(wp);
    const float a[8]  = {a0.x, a0.y, a0.z, a0.w, a1.x, a1.y, a1.z, a1.w};
    const float wr[4] = {wv.x, wv.y, wv.z, wv.w};
#pragma unroll
    for (int i = 0; i < 8; ++i)
#pragma unroll
      for (int j = 0; j < 4; ++j)
        acc[i][j] += a[i] * wr[j];
    ap += 64;
    wp += k4H;
  }
}

// red layout: [4 waves][64 batch][33 (32 cols + pad)]
__device__ __forceinline__ void store_red(float* __restrict__ red, int w,
                                          int bg, int cg, const float acc[8][4]) {
#pragma unroll
  for (int i = 0; i < 8; ++i)
#pragma unroll
    for (int j = 0; j < 4; ++j)
      red[(w * 64 + bg * 8 + i) * 33 + cg * 4 + j] = acc[i][j];
}

// Cross-wave K reduce + batchnorm for cols [w*8, w*8+8). lane = batch.
__device__ __forceinline__ void bn_from_red(const float* __restrict__ red,
                                            int w, int lane, float out[8]) {
#pragma unroll
  for (int k = 0; k < 8; ++k) {
    const int c = w * 8 + k;
    const float v = red[(0 * 64 + lane) * 33 + c]
                  + red[(1 * 64 + lane) * 33 + c]
                  + red[(2 * 64 + lane) * 33 + c]
                  + red[(3 * 64 + lane) * 33 + c];
    const float s = wave_sum64(v);
    const float q = wave_sum64(v * v);
    const float m = s * 0.015625f;
    const float var = q * 0.015625f - m * m;
    out[k] = (v - m) * rsqrtf(var + 1e-5f);
  }
}

// One BN-LSTM layer update for this block's 8 H-columns (base c0h).
__device__ void bnlstm_layer(const float* __restrict__ inA, int KA,
                             const float* __restrict__ WA,
                             const float* __restrict__ inB,
                             const float* __restrict__ WB,
                             const float* __restrict__ bias,
                             const float* __restrict__ gA,
                             const float* __restrict__ gB,
                             const float* __restrict__ gCc,
                             const float* __restrict__ bCc,
                             float* __restrict__ cT,
                             float* __restrict__ hOut,
                             int c0h, int w, int lane,
                             float* __restrict__ redA,
                             float* __restrict__ redB,
                             float* __restrict__ gbuf)
{
  const int bg = lane & 7;         // batch group: batches bg*8 .. bg*8+7
  const int cg = lane >> 3;        // col group:   red-cols cg*4 .. cg*4+3
  // weight column for red-col c = cg*4+j is (c>>3)*1024 + c0h + (c&7)
  const int wcol = (cg >> 1) * 1024 + c0h + (cg & 1) * 4;

  float accA[8][4];
#pragma unroll
  for (int i = 0; i < 8; ++i)
#pragma unroll
    for (int j = 0; j < 4; ++j) accA[i][j] = 0.0f;
  gemm_slice(inA, WA, w * (KA >> 2), KA >> 2, bg, wcol, accA);
  store_red(redA, w, bg, cg, accA);

  float accB[8][4];
#pragma unroll
  for (int i = 0; i < 8; ++i)
#pragma unroll
    for (int j = 0; j < 4; ++j) accB[i][j] = 0.0f;
  gemm_slice(inB, WB, w * 256, 256, bg, wcol, accB);
  store_red(redB, w, bg, cg, accB);

  __syncthreads();

  // cross-wave reduce + BN; wave w owns gate-segment w (cols w*8..w*8+7,
  // i.e. weight cols w*1024 + c0h + k)
  float nA[8], nB[8];
  bn_from_red(redA, w, lane, nA);
  bn_from_red(redB, w, lane, nB);
#pragma unroll
  for (int k = 0; k < 8; ++k) {
    const int gIdx = w * 1024 + c0h + k;   // wave-uniform -> scalar loads
    gbuf[(w * 8 + k) * 64 + lane] = nA[k] * gA[gIdx] + nB[k] * gB[gIdx] + bias[gIdx];
  }
  __syncthreads();

  // cell update: 8 H-cols, 4 waves -> 2 cols per wave; lane = batch
#pragma unroll
  for (int r = 0; r < 2; ++r) {
    const int hc = w + r * 4;
    const int col = c0h + hc;
    const float gi = gbuf[(0 * 8 + hc) * 64 + lane];
    const float gj = gbuf[(1 * 8 + hc) * 64 + lane];
    const float gf = gbuf[(2 * 8 + hc) * 64 + lane];
    const float go = gbuf[(3 * 8 + hc) * 64 + lane];
    const float c_old = cT[col * 64 + lane];
    const float c_new = sigm(gf + 1.0f) * c_old + sigm(gi) * tanhf(gj);
    const float s = wave_sum64(c_new), q = wave_sum64(c_new * c_new);
    const float m = s * 0.015625f;
    const float var = q * 0.015625f - m * m;
    const float cn = gCc[col] * (c_new - m) * rsqrtf(var + 1e-5f) + bCc[col];
    cT[col * 64 + lane] = c_new;
    hOut[col * 64 + lane] = sigm(go) * tanhf(cn);
  }
}

// phase t: blocks 0..127 -> L1(t) (if t>=1); blocks 128..255 -> L0(t) (if t<T).
// The two layer updates within a phase are independent (both read h0T[t&1]).
__global__ __launch_bounds__(256) void phase_k(RecParams P, int t) {
  __shared__ float redA[4 * 64 * 33];
  __shared__ float redB[4 * 64 * 33];
  __shared__ float gbuf[32 * 64];
  const int bid  = blockIdx.x;
  const int w    = __builtin_amdgcn_readfirstlane((int)(threadIdx.x >> 6));
  const int lane = threadIdx.x & 63;

  if (bid < 128) {
    if (t >= 1) {
      bnlstm_layer(P.h0T + (size_t)(t & 1) * kHB, kH, P.Wx1,
                   P.h1hist + (size_t)(t - 1) * kHB, P.Wh1,
                   P.b1, P.gx1, P.gh1, P.gc1, P.bc1,
                   P.c1T, P.h1hist + (size_t)t * kHB,
                   bid * 8, w, lane, redA, redB, gbuf);
    }
  } else {
    if (t < kT) {
      bnlstm_layer(P.xT + (size_t)t * kNU * kB, kNU, P.Wx0,
                   P.h0T + (size_t)(t & 1) * kHB, P.Wh0,
                   P.b0, P.gx0, P.gh0, P.gc0, P.bc0,
                   P.c0T, P.h0T + (size_t)((t + 1) & 1) * kHB,
                   (bid - 128) * 8, w, lane, redA, redB, gbuf);
    }
  }
}

// embedding gather + transpose: xT[t][u][b] = emb[idx[b][t]][u]
__global__ __launch_bounds__(256) void embed_k(const int* __restrict__ idx,
                                               const float* __restrict__ emb,
                                               float* __restrict__ xT) {
  const int t = blockIdx.x;
  __shared__ int rows[kB];
  const int tid = threadIdx.x;
  if (tid < kB) rows[tid] = idx[tid * kT + t];
  __syncthreads();
  float* dst = xT + (size_t)t * kNU * kB;
  for (int i = tid; i < kNU * kB; i += 256) {
    const int u = i >> 6, b = i & 63;
    dst[i] = emb[(size_t)rows[b] * kNU + u];
  }
}

// Y[r = b*T + t][n] = h1(t+1 slot) . Wp[:,n] + bp[n]
__global__ __launch_bounds__(256) void yproj_k(const float* __restrict__ h1hist,
                                               const float* __restrict__ Wp,
                                               const float* __restrict__ bp,
                                               float* __restrict__ Y) {
  const int t  = blockIdx.x;
  const int nq = blockIdx.y;
  const int w    = __builtin_amdgcn_readfirstlane((int)(threadIdx.x >> 6));
  const int lane = threadIdx.x & 63;
  const int n0 = nq * 64 + w * 16;
  const float* hin = h1hist + (size_t)(t + 1) * kHB;
  float acc[16];
#pragma unroll
  for (int k = 0; k < 16; ++k) acc[k] = 0.0f;
#pragma unroll 4
  for (int u = 0; u < kH; ++u) {
    const float xv = hin[u * 64 + lane];
    const float4* wr = (const float4*)(Wp + (size_t)u * kNU + n0);
#pragma unroll
    for (int q = 0; q < 4; ++q) {
      const float4 wv = wr[q];
      acc[q * 4 + 0] += xv * wv.x;
      acc[q * 4 + 1] += xv * wv.y;
      acc[q * 4 + 2] += xv * wv.z;
      acc[q * 4 + 3] += xv * wv.w;
    }
  }
  float* yr = Y + ((size_t)lane * kT + t) * kNU + n0;
#pragma unroll
  for (int k = 0; k < 16; ++k) yr[k] = acc[k] + bp[n0 + k];
}

// logits[r][v] = Y[r][:] . SW[:,v] + sb[v].  Block: 64 r x 128 v, K = 256.
__global__ __launch_bounds__(256) void gemm2_k(const float* __restrict__ Y,
                                               const float* __restrict__ SW,
                                               const float* __restrict__ sb,
                                               float* __restrict__ out) {
  __shared__ float A[64 * 256];   // 64 KB
  const int r0 = blockIdx.x * 64;
  const int v0 = blockIdx.y * 128;
  const int tid = threadIdx.x;
  {
    const float4* src = (const float4*)(Y + (size_t)r0 * kNU);
    float4* dst = (float4*)A;
    for (int i = tid; i < 64 * 64; i += 256) dst[i] = src[i];
  }
  __syncthreads();
  const int tv = tid & 15, tr = tid >> 4;
  const int v = v0 + tv * 8;
  if (v + 7 >= kV) return;   // whole-thread guard (tile tail); barrier already passed
  float acc[4][8];
#pragma unroll
  for (int i = 0; i < 4; ++i)
#pragma unroll
    for (int k = 0; k < 8; ++k) acc[i][k] = 0.0f;

  for (int n = 0; n < 256; ++n) {
    const float4 b0 = *(const float4*)(SW + (size_t)n * kV + v);
    const float4 b1 = *(const float4*)(SW + (size_t)n * kV + v + 4);
#pragma unroll
    for (int i = 0; i < 4; ++i) {
      const float a = A[(tr * 4 + i) * 256 + n];
      acc[i][0] += a * b0.x; acc[i][1] += a * b0.y;
      acc[i][2] += a * b0.z; acc[i][3] += a * b0.w;
      acc[i][4] += a * b1.x; acc[i][5] += a * b1.y;
      acc[i][6] += a * b1.z; acc[i][7] += a * b1.w;
    }
  }
#pragma unroll
  for (int i = 0; i < 4; ++i) {
    const size_t r = (size_t)(r0 + tr * 4 + i);
    float* o = out + r * kV + v;
#pragma unroll
    for (int k = 0; k < 8; ++k) o[k] = acc[i][k] + sb[v + k];
  }
}

extern "C" void kernel_launch(void* const* d_in, const int* in_sizes, int n_in,
                              void* d_out, int out_size, void* d_ws, size_t ws_size,
                              hipStream_t stream) {
  (void)in_sizes; (void)n_in; (void)out_size; (void)ws_size;
  const int*   idx = (const int*)d_in[0];
  const float* emb = (const float*)d_in[1];
  RecParams P;
  P.Wx0 = (const float*)d_in[2];  P.Wh0 = (const float*)d_in[3];
  P.b0  = (const float*)d_in[4];  P.gx0 = (const float*)d_in[5];
  P.gh0 = (const float*)d_in[6];  P.gc0 = (const float*)d_in[7];
  P.bc0 = (const float*)d_in[8];
  P.Wx1 = (const float*)d_in[9];  P.Wh1 = (const float*)d_in[10];
  P.b1  = (const float*)d_in[11]; P.gx1 = (const float*)d_in[12];
  P.gh1 = (const float*)d_in[13]; P.gc1 = (const float*)d_in[14];
  P.bc1 = (const float*)d_in[15];
  const float* Wp = (const float*)d_in[16];
  const float* bp = (const float*)d_in[17];
  const float* SW = (const float*)d_in[18];
  const float* sb = (const float*)d_in[19];

  float* ws = (float*)d_ws;
  size_t off = 0;
  float* xT     = ws + off; off += (size_t)kT * kNU * kB;     // 2,097,152
  float* h0T    = ws + off; off += 2 * (size_t)kHB;           // 131,072
  float* h1hist = ws + off; off += (size_t)(kT + 1) * kHB;    // 8,454,144
  float* c0T    = ws + off; off += kHB;
  float* c1T    = ws + off; off += kHB;
  float* Y      = ws + off; off += (size_t)kT * kB * kNU;     // 2,097,152

  P.xT = xT; P.h0T = h0T; P.h1hist = h1hist; P.c0T = c0T; P.c1T = c1T;

  // zero-init initial states (ws is poisoned 0xAA before every launch)
  hipMemsetAsync(h0T, 0, (size_t)kHB * sizeof(float), stream);          // slot 0 only
  hipMemsetAsync(h1hist, 0, (size_t)kHB * sizeof(float), stream);       // slot 0 only
  hipMemsetAsync(c0T, 0, (size_t)kHB * sizeof(float), stream);
  hipMemsetAsync(c1T, 0, (size_t)kHB * sizeof(float), stream);

  embed_k<<<kT, 256, 0, stream>>>(idx, emb, xT);

  for (int t = 0; t <= kT; ++t)
    phase_k<<<256, 256, 0, stream>>>(P, t);

  yproj_k<<<dim3(kT, 4), 256, 0, stream>>>(h1hist, Wp, bp, Y);

  gemm2_k<<<dim3(8192 / 64, 63), 256, 0, stream>>>(Y, SW, sb, (float*)d_out);
}

// Round 3
// 8240.701 us; speedup vs baseline: 10.9040x; 2.9370x over previous
//
#include <hip/hip_runtime.h>
#include <cstddef>

// ---------------------------------------------------------------------------
// CharRNN BN-LSTM (2 layers, recurrent batch norm) + projection + softmax head
// Round 4: same design as round 3 (16-wave phase blocks, side-split GEMM,
// 1-deep prefetch) but derisked LDS:
//   - phase_k: ONE shared [8][64][33] reduction buffer time-shared between
//     Wx-side and Wh-side (stores sequenced by 2 extra barriers). LDS
//     143 KiB -> 75.8 KiB (within the 128 KiB hardware-proven-good bound).
//   - gemm2_k: A-tile row stride 264 floats (stride = 8 banks -> the 4
//     broadcast rows/wave hit 4 distinct banks; fully conflict-free).
// ---------------------------------------------------------------------------

namespace {
constexpr int kT  = 128;
constexpr int kB  = 64;
constexpr int kNU = 256;
constexpr int kH  = 1024;
constexpr int kV  = 8000;
constexpr int kHB = kH * kB;   // 65536 floats
constexpr int k4H = 4096;
}

__device__ __forceinline__ float wave_sum64(float v) {
#pragma unroll
  for (int off = 32; off > 0; off >>= 1) v += __shfl_xor(v, off, 64);
  return v;
}

__device__ __forceinline__ float sigm(float x) { return 1.0f / (1.0f + expf(-x)); }

struct RecParams {
  const float* xT;      // [T][NU][B]
  float* h0T;           // [2][H][B] double buffer
  float* h1hist;        // [T+1][H][B]
  float* c0T;           // [H][B]
  float* c1T;           // [H][B]
  const float* Wx0; const float* Wh0; const float* b0;
  const float* gx0; const float* gh0; const float* gc0; const float* bc0;
  const float* Wx1; const float* Wh1; const float* b1;
  const float* gx1; const float* gh1; const float* gc1; const float* bc1;
};

// Per-wave K-slice of GEMM: acc[i][j] += act[u][bg*8+i] * W[u][wcol+j]
// act: [K][64] (transposed activations), W: [K][4096] row-major.
// 1-deep software pipeline: next iteration's loads issue before current FMAs.
__device__ __forceinline__ void gemm_slice(const float* __restrict__ act,
                                           const float* __restrict__ W,
                                           int u0, int ks, int bg, int wcol,
                                           float acc[8][4]) {
  const float* ap = act + (size_t)u0 * 64 + bg * 8;
  const float* wp = W + (size_t)u0 * k4H + wcol;
  float4 a0 = *(const float4*)(ap);
  float4 a1 = *(const float4*)(ap + 4);
  float4 wv = *(const float4*)(wp);
#pragma unroll 2
  for (int u = 0; u < ks - 1; ++u) {
    const float4 ca0 = a0, ca1 = a1, cw = wv;
    ap += 64; wp += k4H;
    a0 = *(const float4*)(ap);
    a1 = *(const float4*)(ap + 4);
    wv = *(const float4*)(wp);
    const float a[8]  = {ca0.x, ca0.y, ca0.z, ca0.w, ca1.x, ca1.y, ca1.z, ca1.w};
    const float wr[4] = {cw.x, cw.y, cw.z, cw.w};
#pragma unroll
    for (int i = 0; i < 8; ++i)
#pragma unroll
      for (int j = 0; j < 4; ++j)
        acc[i][j] += a[i] * wr[j];
  }
  {
    const float a[8]  = {a0.x, a0.y, a0.z, a0.w, a1.x, a1.y, a1.z, a1.w};
    const float wr[4] = {wv.x, wv.y, wv.z, wv.w};
#pragma unroll
    for (int i = 0; i < 8; ++i)
#pragma unroll
      for (int j = 0; j < 4; ++j)
        acc[i][j] += a[i] * wr[j];
  }
}

// red layout: [8 slices][64 batch][33 (32 cols + pad)]
__device__ __forceinline__ void store_red(float* __restrict__ red, int ws,
                                          int bg, int cg, const float acc[8][4]) {
#pragma unroll
  for (int i = 0; i < 8; ++i)
#pragma unroll
    for (int j = 0; j < 4; ++j)
      red[(ws * 64 + bg * 8 + i) * 33 + cg * 4 + j] = acc[i][j];
}

// Cross-slice reduce for this wave's two columns c = 2w, 2w+1. lane = batch.
__device__ __forceinline__ void reduce_red(const float* __restrict__ red,
                                           int w, int lane, float out[2]) {
#pragma unroll
  for (int r = 0; r < 2; ++r) {
    const int c = 2 * w + r;
    float v = 0.0f;
#pragma unroll
    for (int s = 0; s < 8; ++s) v += red[(s * 64 + lane) * 33 + c];
    out[r] = v;
  }
}

// One BN-LSTM layer update for this block's 8 H-columns (base c0h).
// 16 waves: waves 0-7 = Wx-side GEMM (K split 8 ways), waves 8-15 = Wh-side.
// Both sides compute concurrently; the single red buffer is time-shared.
__device__ void bnlstm_layer(const float* __restrict__ inA, int KA,
                             const float* __restrict__ WA,
                             const float* __restrict__ inB,
                             const float* __restrict__ WB,
                             const float* __restrict__ bias,
                             const float* __restrict__ gA,
                             const float* __restrict__ gB,
                             const float* __restrict__ gCc,
                             const float* __restrict__ bCc,
                             float* __restrict__ cT,
                             float* __restrict__ hOut,
                             int c0h, int w, int lane,
                             float* __restrict__ red,
                             float* __restrict__ gbuf)
{
  const int side = w >> 3;         // 0 = Wx-side, 1 = Wh-side
  const int ws   = w & 7;          // K-slice index within side
  const int bg = lane & 7;         // batch group: batches bg*8 .. bg*8+7
  const int cg = lane >> 3;        // col group:   red-cols cg*4 .. cg*4+3
  // weight column for red-col c = cg*4+j is (c>>3)*1024 + c0h + (c&7)
  const int wcol = (cg >> 1) * 1024 + c0h + (cg & 1) * 4;

  float acc[8][4];
#pragma unroll
  for (int i = 0; i < 8; ++i)
#pragma unroll
    for (int j = 0; j < 4; ++j) acc[i][j] = 0.0f;

  if (side == 0) {
    gemm_slice(inA, WA, ws * (KA >> 3), KA >> 3, bg, wcol, acc);
    store_red(red, ws, bg, cg, acc);           // Wx-side stores first
  } else {
    gemm_slice(inB, WB, ws * 128, 128, bg, wcol, acc);  // hold acc in regs
  }
  __syncthreads();

  float vA[2], vB[2];
  reduce_red(red, w, lane, vA);                // Wx-side partials
  __syncthreads();
  if (side == 1) store_red(red, ws, bg, cg, acc);       // Wh-side stores
  __syncthreads();
  reduce_red(red, w, lane, vB);                // Wh-side partials

  // BN + gate pre-activation for this wave's two cols. lane = batch.
#pragma unroll
  for (int r = 0; r < 2; ++r) {
    const int c = 2 * w + r;
    const float sA = wave_sum64(vA[r]), qA = wave_sum64(vA[r] * vA[r]);
    const float sB = wave_sum64(vB[r]), qB = wave_sum64(vB[r] * vB[r]);
    const float mA = sA * 0.015625f, mB = sB * 0.015625f;
    const float varA = qA * 0.015625f - mA * mA;
    const float varB = qB * 0.015625f - mB * mB;
    const float nA = (vA[r] - mA) * rsqrtf(varA + 1e-5f);
    const float nB = (vB[r] - mB) * rsqrtf(varB + 1e-5f);
    const int gIdx = (c >> 3) * 1024 + c0h + (c & 7);   // wave-uniform
    gbuf[c * 64 + lane] = nA * gA[gIdx] + nB * gB[gIdx] + bias[gIdx];
  }
  __syncthreads();

  // cell update: 8 H-cols, waves 0-7 take one col each; lane = batch
  if (w < 8) {
    const int hc = w;
    const int col = c0h + hc;
    const float gi = gbuf[(0 * 8 + hc) * 64 + lane];
    const float gj = gbuf[(1 * 8 + hc) * 64 + lane];
    const float gf = gbuf[(2 * 8 + hc) * 64 + lane];
    const float go = gbuf[(3 * 8 + hc) * 64 + lane];
    const float c_old = cT[col * 64 + lane];
    const float c_new = sigm(gf + 1.0f) * c_old + sigm(gi) * tanhf(gj);
    const float s = wave_sum64(c_new), q = wave_sum64(c_new * c_new);
    const float m = s * 0.015625f;
    const float var = q * 0.015625f - m * m;
    const float cn = gCc[col] * (c_new - m) * rsqrtf(var + 1e-5f) + bCc[col];
    cT[col * 64 + lane] = c_new;
    hOut[col * 64 + lane] = sigm(go) * tanhf(cn);
  }
}

// phase t: blocks 0..127 -> L1(t) (if t>=1); blocks 128..255 -> L0(t) (if t<T).
// The two layer updates within a phase are independent (both read h0T[t&1]).
__global__ __launch_bounds__(1024) void phase_k(RecParams P, int t) {
  __shared__ float red[8 * 64 * 33];    // 67.6 KB
  __shared__ float gbuf[32 * 64];       //  8.2 KB
  const int bid  = blockIdx.x;
  const int w    = __builtin_amdgcn_readfirstlane((int)(threadIdx.x >> 6));
  const int lane = threadIdx.x & 63;

  if (bid < 128) {
    if (t >= 1) {
      bnlstm_layer(P.h0T + (size_t)(t & 1) * kHB, kH, P.Wx1,
                   P.h1hist + (size_t)(t - 1) * kHB, P.Wh1,
                   P.b1, P.gx1, P.gh1, P.gc1, P.bc1,
                   P.c1T, P.h1hist + (size_t)t * kHB,
                   bid * 8, w, lane, red, gbuf);
    }
  } else {
    if (t < kT) {
      bnlstm_layer(P.xT + (size_t)t * kNU * kB, kNU, P.Wx0,
                   P.h0T + (size_t)(t & 1) * kHB, P.Wh0,
                   P.b0, P.gx0, P.gh0, P.gc0, P.bc0,
                   P.c0T, P.h0T + (size_t)((t + 1) & 1) * kHB,
                   (bid - 128) * 8, w, lane, red, gbuf);
    }
  }
}

// embedding gather + transpose: xT[t][u][b] = emb[idx[b][t]][u]
__global__ __launch_bounds__(256) void embed_k(const int* __restrict__ idx,
                                               const float* __restrict__ emb,
                                               float* __restrict__ xT) {
  const int t = blockIdx.x;
  __shared__ int rows[kB];
  const int tid = threadIdx.x;
  if (tid < kB) rows[tid] = idx[tid * kT + t];
  __syncthreads();
  float* dst = xT + (size_t)t * kNU * kB;
  for (int i = tid; i < kNU * kB; i += 256) {
    const int u = i >> 6, b = i & 63;
    dst[i] = emb[(size_t)rows[b] * kNU + u];
  }
}

// Y[r = b*T + t][n] = h1(t+1 slot) . Wp[:,n] + bp[n]
__global__ __launch_bounds__(256) void yproj_k(const float* __restrict__ h1hist,
                                               const float* __restrict__ Wp,
                                               const float* __restrict__ bp,
                                               float* __restrict__ Y) {
  const int t  = blockIdx.x;
  const int nq = blockIdx.y;
  const int w    = __builtin_amdgcn_readfirstlane((int)(threadIdx.x >> 6));
  const int lane = threadIdx.x & 63;
  const int n0 = nq * 64 + w * 16;
  const float* hin = h1hist + (size_t)(t + 1) * kHB;
  float acc[16];
#pragma unroll
  for (int k = 0; k < 16; ++k) acc[k] = 0.0f;
#pragma unroll 4
  for (int u = 0; u < kH; ++u) {
    const float xv = hin[u * 64 + lane];
    const float4* wr = (const float4*)(Wp + (size_t)u * kNU + n0);
#pragma unroll
    for (int q = 0; q < 4; ++q) {
      const float4 wv = wr[q];
      acc[q * 4 + 0] += xv * wv.x;
      acc[q * 4 + 1] += xv * wv.y;
      acc[q * 4 + 2] += xv * wv.z;
      acc[q * 4 + 3] += xv * wv.w;
    }
  }
  float* yr = Y + ((size_t)lane * kT + t) * kNU + n0;
#pragma unroll
  for (int k = 0; k < 16; ++k) yr[k] = acc[k] + bp[n0 + k];
}

// logits[r][v] = Y[r][:] . SW[:,v] + sb[v].  Block: 64 r x 128 v, K = 256.
// A-tile row stride 264 floats: 264 mod 32 = 8 banks -> the 4 broadcast rows
// per wave (r, r+4, r+8, r+12) land on banks +0/+8/+16/+24: conflict-free.
__global__ __launch_bounds__(256) void gemm2_k(const float* __restrict__ Y,
                                               const float* __restrict__ SW,
                                               const float* __restrict__ sb,
                                               float* __restrict__ out) {
  constexpr int kAS = 264;
  __shared__ float A[64 * kAS];   // 67.6 KB
  const int r0 = blockIdx.x * 64;
  const int v0 = blockIdx.y * 128;
  const int tid = threadIdx.x;
  {
    const float4* src = (const float4*)(Y + (size_t)r0 * kNU);
    for (int i = tid; i < 64 * 64; i += 256) {
      const float4 v = src[i];
      *(float4*)(A + (i >> 6) * kAS + (i & 63) * 4) = v;
    }
  }
  __syncthreads();
  const int tv = tid & 15, tr = tid >> 4;
  const int v = v0 + tv * 8;
  if (v + 7 >= kV) return;   // whole-thread guard (tile tail); barrier already passed
  float acc[4][8];
#pragma unroll
  for (int i = 0; i < 4; ++i)
#pragma unroll
    for (int k = 0; k < 8; ++k) acc[i][k] = 0.0f;

  for (int n = 0; n < 256; ++n) {
    const float4 b0 = *(const float4*)(SW + (size_t)n * kV + v);
    const float4 b1 = *(const float4*)(SW + (size_t)n * kV + v + 4);
#pragma unroll
    for (int i = 0; i < 4; ++i) {
      const float a = A[(tr * 4 + i) * kAS + n];
      acc[i][0] += a * b0.x; acc[i][1] += a * b0.y;
      acc[i][2] += a * b0.z; acc[i][3] += a * b0.w;
      acc[i][4] += a * b1.x; acc[i][5] += a * b1.y;
      acc[i][6] += a * b1.z; acc[i][7] += a * b1.w;
    }
  }
#pragma unroll
  for (int i = 0; i < 4; ++i) {
    const size_t r = (size_t)(r0 + tr * 4 + i);
    float* o = out + r * kV + v;
#pragma unroll
    for (int k = 0; k < 8; ++k) o[k] = acc[i][k] + sb[v + k];
  }
}

extern "C" void kernel_launch(void* const* d_in, const int* in_sizes, int n_in,
                              void* d_out, int out_size, void* d_ws, size_t ws_size,
                              hipStream_t stream) {
  (void)in_sizes; (void)n_in; (void)out_size; (void)ws_size;
  const int*   idx = (const int*)d_in[0];
  const float* emb = (const float*)d_in[1];
  RecParams P;
  P.Wx0 = (const float*)d_in[2];  P.Wh0 = (const float*)d_in[3];
  P.b0  = (const float*)d_in[4];  P.gx0 = (const float*)d_in[5];
  P.gh0 = (const float*)d_in[6];  P.gc0 = (const float*)d_in[7];
  P.bc0 = (const float*)d_in[8];
  P.Wx1 = (const float*)d_in[9];  P.Wh1 = (const float*)d_in[10];
  P.b1  = (const float*)d_in[11]; P.gx1 = (const float*)d_in[12];
  P.gh1 = (const float*)d_in[13]; P.gc1 = (const float*)d_in[14];
  P.bc1 = (const float*)d_in[15];
  const float* Wp = (const float*)d_in[16];
  const float* bp = (const float*)d_in[17];
  const float* SW = (const float*)d_in[18];
  const float* sb = (const float*)d_in[19];

  float* ws = (float*)d_ws;
  size_t off = 0;
  float* xT     = ws + off; off += (size_t)kT * kNU * kB;     // 2,097,152
  float* h0T    = ws + off; off += 2 * (size_t)kHB;           // 131,072
  float* h1hist = ws + off; off += (size_t)(kT + 1) * kHB;    // 8,454,144
  float* c0T    = ws + off; off += kHB;
  float* c1T    = ws + off; off += kHB;
  float* Y      = ws + off; off += (size_t)kT * kB * kNU;     // 2,097,152

  P.xT = xT; P.h0T = h0T; P.h1hist = h1hist; P.c0T = c0T; P.c1T = c1T;

  // zero-init initial states (ws is poisoned 0xAA before every launch)
  hipMemsetAsync(h0T, 0, (size_t)kHB * sizeof(float), stream);          // slot 0 only
  hipMemsetAsync(h1hist, 0, (size_t)kHB * sizeof(float), stream);       // slot 0 only
  hipMemsetAsync(c0T, 0, (size_t)kHB * sizeof(float), stream);
  hipMemsetAsync(c1T, 0, (size_t)kHB * sizeof(float), stream);

  embed_k<<<kT, 256, 0, stream>>>(idx, emb, xT);

  for (int t = 0; t <= kT; ++t)
    phase_k<<<256, 1024, 0, stream>>>(P, t);

  yproj_k<<<dim3(kT, 4), 256, 0, stream>>>(h1hist, Wp, bp, Y);

  gemm2_k<<<dim3(8192 / 64, 63), 256, 0, stream>>>(Y, SW, sb, (float*)d_out);
}